// Round 1
// baseline (2683.494 us; speedup 1.0000x reference)
//
#include <hip/hip_runtime.h>
#include <cstdint>

typedef __attribute__((ext_vector_type(8))) short short8;
typedef __attribute__((ext_vector_type(4))) float f32x4;

static __device__ __forceinline__ unsigned short f2bf(float f) {
  union { float f; unsigned u; } x; x.f = f;
  return (unsigned short)((x.u + 0x7FFFu + ((x.u >> 16) & 1u)) >> 16);
}

static __device__ __forceinline__ float wred_max(float v) {
#pragma unroll
  for (int o = 32; o > 0; o >>= 1) v = fmaxf(v, __shfl_xor(v, o, 64));
  return v;
}
static __device__ __forceinline__ float wred_sum(float v) {
#pragma unroll
  for (int o = 32; o > 0; o >>= 1) v += __shfl_xor(v, o, 64);
  return v;
}

// ---------------------------------------------------------------------------
// Generic batched bf16-MFMA GEMM:
//   C[z][row][col] = scale * sum_k (A(+A1))[z][row][k] * Bt[z][col][k] + bias[col]
// A, A1, Bt are fp32 in HBM, converted to bf16 during LDS staging.
// Per-operand batch offset = (z/zi)*so + (z%zi)*si.  C addr = cb + row*crs + col*ccs.
// ---------------------------------------------------------------------------
struct GemmP {
  const float* A; const float* A1; const float* B; float* C; const float* bias;
  int M, N, K, lda, ldb, crs, ccs;
  int azi, bzi, czi;
  long aso, asi, bso, bsi, cso, csi;
  float scale; int relu;
};

__global__ __launch_bounds__(256) void gemm_bf16(GemmP p) {
  const int tid = threadIdx.x;
  const int z = blockIdx.z;
  const int tm = blockIdx.y * 128;
  const int tn = blockIdx.x * 128;
  const long ab = (long)(z / p.azi) * p.aso + (long)(z % p.azi) * p.asi;
  const long bb = (long)(z / p.bzi) * p.bso + (long)(z % p.bzi) * p.bsi;
  const long cb = (long)(z / p.czi) * p.cso + (long)(z % p.czi) * p.csi;

  __shared__ __align__(16) short Al[128 * 32];
  __shared__ __align__(16) short Bl[128 * 32];

  f32x4 acc[4][4];
#pragma unroll
  for (int i = 0; i < 4; ++i)
#pragma unroll
    for (int j = 0; j < 4; ++j) acc[i][j] = (f32x4)(0.0f);

  const int lane = tid & 63;
  const int w = tid >> 6;
  const int wr = w >> 1, wc = w & 1;
  const int lr = lane & 15;
  const int lk = (lane >> 4) * 8;

  for (int k0 = 0; k0 < p.K; k0 += 32) {
    // ---- stage A and B tiles (fp32 -> bf16) ----
#pragma unroll
    for (int j = 0; j < 2; ++j) {
      const int flat = (j * 256 + tid) * 8;
      const int row = flat >> 5;
      const int kk = flat & 31;
      // A tile
      {
        const int gr = tm + row;
        float v[8];
        if (gr < p.M) {
          const float* s = p.A + ab + (long)gr * p.lda + k0 + kk;
          f32x4 p0 = *(const f32x4*)s;
          f32x4 p1 = *(const f32x4*)(s + 4);
          if (p.A1) {
            const float* s1 = p.A1 + ab + (long)gr * p.lda + k0 + kk;
            p0 += *(const f32x4*)s1;
            p1 += *(const f32x4*)(s1 + 4);
          }
#pragma unroll
          for (int c = 0; c < 4; ++c) { v[c] = p0[c]; v[c + 4] = p1[c]; }
        } else {
#pragma unroll
          for (int c = 0; c < 8; ++c) v[c] = 0.0f;
        }
        short8 o;
#pragma unroll
        for (int c = 0; c < 8; ++c) o[c] = (short)f2bf(v[c]);
        *(short8*)&Al[flat] = o;
      }
      // B tile (rows are output columns; Bt is [N][K] row-major)
      {
        const int gr = tn + row;
        float v[8];
        if (gr < p.N) {
          const float* s = p.B + bb + (long)gr * p.ldb + k0 + kk;
          f32x4 p0 = *(const f32x4*)s;
          f32x4 p1 = *(const f32x4*)(s + 4);
#pragma unroll
          for (int c = 0; c < 4; ++c) { v[c] = p0[c]; v[c + 4] = p1[c]; }
        } else {
#pragma unroll
          for (int c = 0; c < 8; ++c) v[c] = 0.0f;
        }
        short8 o;
#pragma unroll
        for (int c = 0; c < 8; ++c) o[c] = (short)f2bf(v[c]);
        *(short8*)&Bl[flat] = o;
      }
    }
    __syncthreads();

    short8 af[4], bfv[4];
#pragma unroll
    for (int mi = 0; mi < 4; ++mi)
      af[mi] = *(const short8*)&Al[(wr * 64 + mi * 16 + lr) * 32 + lk];
#pragma unroll
    for (int ni = 0; ni < 4; ++ni)
      bfv[ni] = *(const short8*)&Bl[(wc * 64 + ni * 16 + lr) * 32 + lk];
#pragma unroll
    for (int mi = 0; mi < 4; ++mi)
#pragma unroll
      for (int ni = 0; ni < 4; ++ni)
        acc[mi][ni] = __builtin_amdgcn_mfma_f32_16x16x32_bf16(af[mi], bfv[ni], acc[mi][ni], 0, 0, 0);
    __syncthreads();
  }

  // ---- epilogue ----
  const int kg = (lane >> 4) * 4;
#pragma unroll
  for (int ni = 0; ni < 4; ++ni) {
    const int col = tn + wc * 64 + ni * 16 + lr;
    if (col >= p.N) continue;
    const float bv = p.bias ? p.bias[col] : 0.0f;
#pragma unroll
    for (int mi = 0; mi < 4; ++mi) {
      const int rb = tm + wr * 64 + mi * 16 + kg;
#pragma unroll
      for (int r = 0; r < 4; ++r) {
        const int rw = rb + r;
        if (rw < p.M) {
          float v2 = acc[mi][ni][r] * p.scale + bv;
          if (p.relu) v2 = fmaxf(v2, 0.0f);
          p.C[cb + (long)rw * p.crs + (long)col * p.ccs] = v2;
        }
      }
    }
  }
}

// ---------------------------------------------------------------------------
// softmax over rows of length 1024, in place (one wave per row)
// ---------------------------------------------------------------------------
__global__ __launch_bounds__(256) void softmax1024(float* S) {
  const int row = blockIdx.x * 4 + (threadIdx.x >> 6);
  const int lane = threadIdx.x & 63;
  float* p = S + (long)row * 1024;
  f32x4 v[4];
#pragma unroll
  for (int i = 0; i < 4; ++i) v[i] = *(const f32x4*)&p[(i * 64 + lane) * 4];
  float mx = -3e38f;
#pragma unroll
  for (int i = 0; i < 4; ++i)
#pragma unroll
    for (int j = 0; j < 4; ++j) mx = fmaxf(mx, v[i][j]);
  mx = wred_max(mx);
  float sm = 0.f;
#pragma unroll
  for (int i = 0; i < 4; ++i)
#pragma unroll
    for (int j = 0; j < 4; ++j) { v[i][j] = __expf(v[i][j] - mx); sm += v[i][j]; }
  sm = wred_sum(sm);
  const float inv = 1.0f / sm;
#pragma unroll
  for (int i = 0; i < 4; ++i) {
#pragma unroll
    for (int j = 0; j < 4; ++j) v[i][j] *= inv;
    *(f32x4*)&p[(i * 64 + lane) * 4] = v[i];
  }
}

// ---------------------------------------------------------------------------
// LayerNorm over D=512, one wave per row. resmode: 0 none, 1 full, 2 broadcast[B=2,512]
// ---------------------------------------------------------------------------
__global__ __launch_bounds__(256) void ln512(const float* a, const float* res, int resmode,
                                             const float* g, const float* bt,
                                             float* out) {
  const int row = blockIdx.x * 4 + (threadIdx.x >> 6);
  const int lane = threadIdx.x & 63;
  const float* ar = a + (long)row * 512;
  f32x4 x[2];
#pragma unroll
  for (int i = 0; i < 2; ++i) {
    const int idx = (i * 64 + lane) * 4;
    x[i] = *(const f32x4*)&ar[idx];
    if (resmode == 1) x[i] += *(const f32x4*)&res[(long)row * 512 + idx];
    else if (resmode == 2) x[i] += *(const f32x4*)&res[(row & 1) * 512 + idx];
  }
  float s = 0.f;
#pragma unroll
  for (int i = 0; i < 2; ++i)
#pragma unroll
    for (int j = 0; j < 4; ++j) s += x[i][j];
  const float mean = wred_sum(s) * (1.0f / 512.0f);
  float vv = 0.f;
#pragma unroll
  for (int i = 0; i < 2; ++i)
#pragma unroll
    for (int j = 0; j < 4; ++j) { const float d = x[i][j] - mean; vv += d * d; }
  vv = wred_sum(vv) * (1.0f / 512.0f);
  const float rs = rsqrtf(vv + 1e-5f);
#pragma unroll
  for (int i = 0; i < 2; ++i) {
    const int idx = (i * 64 + lane) * 4;
    const f32x4 gv = *(const f32x4*)&g[idx];
    const f32x4 bv = *(const f32x4*)&bt[idx];
    f32x4 o;
#pragma unroll
    for (int j = 0; j < 4; ++j) o[j] = (x[i][j] - mean) * rs * gv[j] + bv[j];
    *(f32x4*)&out[(long)row * 512 + idx] = o;
  }
}

// ---------------------------------------------------------------------------
// custom attention small kernels (fp32)
// ---------------------------------------------------------------------------
// xsum[b][d] = sum_n (x1 + qpos)[(n*2+b)*512 + d]
__global__ __launch_bounds__(512) void xsum_k(const float* x1, const float* qpos, float* xs) {
  const int b = blockIdx.x;
  const int d = threadIdx.x;
  float acc = 0.f;
  for (int n = 0; n < 1024; ++n) {
    const long i = ((long)(n * 2 + b)) * 512 + d;
    acc += x1[i] + qpos[i];
  }
  xs[b * 512 + d] = acc;
}

// qsum[o]=W0[o,:]*xsum + 1024*b0[o]; s1[b,h,m] = 0.125*sum_d qsum[d*8+h]*kT[b][d*8+h][m]
__global__ __launch_bounds__(256) void qs_s1_k(const float* xs, const float* W0, const float* b0,
                                               const float* kT, float* s1) {
  const int z = blockIdx.x, b = z >> 3, h = z & 7;
  const int tid = threadIdx.x;
  __shared__ float xsl[512];
  __shared__ float part[4][64];
  __shared__ float qs[64];
  xsl[tid] = xs[b * 512 + tid];
  xsl[tid + 256] = xs[b * 512 + tid + 256];
  __syncthreads();
  const int d = tid & 63, pt = tid >> 6;
  const int o = d * 8 + h;
  float pp = 0.f;
  for (int dd = pt * 128; dd < pt * 128 + 128; ++dd) pp += W0[(long)o * 512 + dd] * xsl[dd];
  part[pt][d] = pp;
  __syncthreads();
  if (tid < 64)
    qs[tid] = part[0][tid] + part[1][tid] + part[2][tid] + part[3][tid] + 1024.0f * b0[tid * 8 + h];
  __syncthreads();
#pragma unroll
  for (int i = 0; i < 8; ++i) {
    const int m = tid + i * 256;
    float sacc = 0.f;
#pragma unroll 8
    for (int d2 = 0; d2 < 64; ++d2)
      sacc += qs[d2] * kT[((long)b * 512 + d2 * 8 + h) * 2048 + m];
    s1[(long)z * 2048 + m] = 0.125f * sacc;
  }
}

// per (b,h): for n in 0..63: row = kT[b][n*8+h][:]*s1[b,h,:]; softmax over m; pw += mw[n]*prob
__global__ __launch_bounds__(256) void pw_k(const float* kT, const float* s1,
                                            const float* mw, float* pw) {
  const int z = blockIdx.x, b = z >> 3, h = z & 7;
  const int tid = threadIdx.x, lane = tid & 63, wid = tid >> 6;
  __shared__ float redm[4], reds[4];
  float s1v[8], pwa[8];
#pragma unroll
  for (int i = 0; i < 8; ++i) { s1v[i] = s1[(long)z * 2048 + tid + i * 256]; pwa[i] = 0.f; }
  for (int n = 0; n < 64; ++n) {
    const float* kr = kT + ((long)b * 512 + n * 8 + h) * 2048;
    float sv[8];
    float mx = -3e38f;
#pragma unroll
    for (int i = 0; i < 8; ++i) { sv[i] = kr[tid + i * 256] * s1v[i]; mx = fmaxf(mx, sv[i]); }
    mx = wred_max(mx);
    if (lane == 0) redm[wid] = mx;
    __syncthreads();
    mx = fmaxf(fmaxf(redm[0], redm[1]), fmaxf(redm[2], redm[3]));
    float sm = 0.f;
#pragma unroll
    for (int i = 0; i < 8; ++i) { sv[i] = __expf(sv[i] - mx); sm += sv[i]; }
    sm = wred_sum(sm);
    if (lane == 0) reds[wid] = sm;
    __syncthreads();
    sm = reds[0] + reds[1] + reds[2] + reds[3];
    const float wnl = mw[n] / sm;
#pragma unroll
    for (int i = 0; i < 8; ++i) pwa[i] += wnl * sv[i];
    __syncthreads();
  }
#pragma unroll
  for (int i = 0; i < 8; ++i) pw[(long)z * 2048 + tid + i * 256] = pwa[i];
}

// t2c[b][d*8+h] = sum_m vT[b][d*8+h][m]*pw[b,h,m] + mb
__global__ __launch_bounds__(256) void x2_k(const float* vT, const float* pw,
                                            const float* mb, float* t2c) {
  const int z = blockIdx.x, b = z >> 3, h = z & 7;
  const int tid = threadIdx.x, lane = tid & 63, wid = tid >> 6;
  const float* pr = pw + (long)z * 2048;
  for (int ci = 0; ci < 16; ++ci) {
    const int d = wid * 16 + ci, ch = d * 8 + h;
    const float* vr = vT + ((long)b * 512 + ch) * 2048;
    float acc = 0.f;
#pragma unroll 8
    for (int i = 0; i < 32; ++i) acc += vr[lane + i * 64] * pr[lane + i * 64];
    acc = wred_sum(acc);
    if (lane == 0) t2c[b * 512 + ch] = acc + mb[0];
  }
}

// ---------------------------------------------------------------------------
static inline GemmP mk(const float* A, const float* B, float* C, int M, int N, int K,
                       int lda, int ldb, int crs) {
  GemmP p{};
  p.A = A; p.A1 = nullptr; p.B = B; p.C = C; p.bias = nullptr;
  p.M = M; p.N = N; p.K = K; p.lda = lda; p.ldb = ldb; p.crs = crs; p.ccs = 1;
  p.azi = p.bzi = p.czi = 1;
  p.aso = p.asi = p.bso = p.bsi = p.cso = p.csi = 0;
  p.scale = 1.0f; p.relu = 0;
  return p;
}

static inline void launch_gemm(const GemmP& p, int nb, hipStream_t s) {
  dim3 grid((p.N + 127) / 128, (p.M + 127) / 128, nb);
  gemm_bf16<<<grid, dim3(256), 0, s>>>(p);
}

extern "C" void kernel_launch(void* const* d_in, const int* in_sizes, int n_in,
                              void* d_out, int out_size, void* d_ws, size_t ws_size,
                              hipStream_t stream) {
  (void)in_sizes; (void)n_in; (void)out_size; (void)ws_size;
  const float* tgt   = (const float*)d_in[0];
  const float* memry = (const float*)d_in[1];
  const float* qpos  = (const float*)d_in[2];
  const float* pos   = (const float*)d_in[3];
  const float* ipw   = (const float*)d_in[4];
  const float* ipb   = (const float*)d_in[5];
  const float* outw  = (const float*)d_in[6];
  const float* outb  = (const float*)d_in[7];
  const float* convw = (const float*)d_in[8];
  const float* convb = (const float*)d_in[9];
  const float* mlpw  = (const float*)d_in[10];
  const float* mlpb  = (const float*)d_in[11];
  const float* l1w   = (const float*)d_in[12];
  const float* l1b   = (const float*)d_in[13];
  const float* l2w   = (const float*)d_in[14];
  const float* l2b   = (const float*)d_in[15];
  const float* lng   = (const float*)d_in[16];
  const float* lnbp  = (const float*)d_in[17];
  const float* fg    = (const float*)d_in[18];
  const float* fbv   = (const float*)d_in[19];
  float* ws = (float*)d_ws;

  const long MB = 1048576;
  float* qk    = ws;             // [2048,1024]   2M floats
  float* Vt    = ws + 2 * MB;    // [16][64][1024] 1M
  float* S     = ws + 3 * MB;    // [16][1024][1024] 16M
  float* attnO = ws + 19 * MB;   // [2048,512] 1M
  float* t2    = ws + 20 * MB;   // 1M
  float* x1    = ws + 21 * MB;   // 1M
  float* kT    = ws + 22 * MB;   // [2][512][2048] 2M
  float* vT    = ws + 24 * MB;   // 2M
  float* x2n   = ws + 26 * MB;   // 1M
  float* hbuf  = ws + 27 * MB;   // [2048,2048] 4M
  float* fbuf  = ws + 31 * MB;   // 1M
  float* xbuf  = ws + 32 * MB;   // 1M
  float* xsumb = ws + 33 * MB;          // [2][512]
  float* s1b   = xsumb + 2048;          // [16][2048]
  float* pwb   = s1b + 32768;           // [16][2048]
  float* t2c   = pwb + 32768;           // [2][512]

  for (int l = 0; l < 4; ++l) {
    const float* xin = l ? xbuf : tgt;

    // 1. q,k projections: (x+qpos) @ wq|wk^T + b  -> qk [2048,1024]
    {
      GemmP p = mk(xin, ipw + (long)l * 786432, qk, 2048, 1024, 512, 512, 512, 1024);
      p.A1 = qpos; p.bias = ipb + (long)l * 1536;
      launch_gemm(p, 1, stream);
    }
    // 2. v projection -> Vt[b][c][n] (transposed C), batched over b
    {
      GemmP p = mk(xin, ipw + (long)l * 786432 + 524288, Vt, 1024, 512, 512, 1024, 512, 1);
      p.ccs = 1024; p.aso = 512; p.cso = 524288;
      p.bias = ipb + (long)l * 1536 + 1024;
      launch_gemm(p, 2, stream);
    }
    // 3. S[z][n][m] = 0.125 * qh·kh^T  (z = b*8+h)
    {
      GemmP p = mk(qk, qk + 512, S, 1024, 1024, 64, 2048, 2048, 1024);
      p.azi = 8; p.aso = 1024; p.asi = 64;
      p.bzi = 8; p.bso = 1024; p.bsi = 64;
      p.cso = MB;
      p.scale = 0.125f;
      launch_gemm(p, 16, stream);
    }
    // 4. softmax rows of S
    softmax1024<<<dim3(4096), dim3(256), 0, stream>>>(S);
    // 5. attnO[(n*2+b)*512 + h*64+d] = P @ Vh
    {
      GemmP p = mk(S, Vt, attnO, 1024, 64, 1024, 1024, 1024, 1024);
      p.aso = MB;
      p.bzi = 8; p.bso = 524288; p.bsi = 65536;
      p.czi = 8; p.cso = 512; p.csi = 64;
      launch_gemm(p, 16, stream);
    }
    // 6. out projection -> t2
    {
      GemmP p = mk(attnO, outw + (long)l * 262144, t2, 2048, 512, 512, 512, 512, 512);
      p.bias = outb + l * 512;
      launch_gemm(p, 1, stream);
    }
    // 7. LN1: x1 = LN(xin + t2)
    ln512<<<dim3(512), dim3(256), 0, stream>>>(t2, xin, 1, lng + (l * 3 + 0) * 512,
                                               lnbp + (l * 3 + 0) * 512, x1);
    // 8. kT[b][c][m] = conv1 proj of (memory+pos), transposed C, batched over b
    {
      GemmP p = mk(memry, convw + ((long)l * 3 + 1) * 262144, kT, 2048, 512, 512, 1024, 512, 1);
      p.A1 = pos; p.aso = 512; p.ccs = 2048; p.cso = MB;
      p.bias = convb + (l * 3 + 1) * 512;
      launch_gemm(p, 2, stream);
    }
    // 9. vT[b][c][m] = conv2 proj of memory
    {
      GemmP p = mk(memry, convw + ((long)l * 3 + 2) * 262144, vT, 2048, 512, 512, 1024, 512, 1);
      p.aso = 512; p.ccs = 2048; p.cso = MB;
      p.bias = convb + (l * 3 + 2) * 512;
      launch_gemm(p, 2, stream);
    }
    // 10-13. custom attention
    xsum_k<<<dim3(2), dim3(512), 0, stream>>>(x1, qpos, xsumb);
    qs_s1_k<<<dim3(16), dim3(256), 0, stream>>>(xsumb, convw + ((long)l * 3) * 262144,
                                                convb + (l * 3) * 512, kT, s1b);
    pw_k<<<dim3(16), dim3(256), 0, stream>>>(kT, s1b, mlpw + l * 64, pwb);
    x2_k<<<dim3(16), dim3(256), 0, stream>>>(vT, pwb, mlpb + l, t2c);
    // 14. LN2: x2n = LN(x1 + broadcast t2c)
    ln512<<<dim3(512), dim3(256), 0, stream>>>(x1, t2c, 2, lng + (l * 3 + 1) * 512,
                                               lnbp + (l * 3 + 1) * 512, x2n);
    // 15. lin1 + ReLU -> hbuf
    {
      GemmP p = mk(x2n, l1w + (long)l * 1048576, hbuf, 2048, 2048, 512, 512, 512, 2048);
      p.bias = l1b + l * 2048; p.relu = 1;
      launch_gemm(p, 1, stream);
    }
    // 16. lin2 -> fbuf
    {
      GemmP p = mk(hbuf, l2w + (long)l * 1048576, fbuf, 2048, 512, 2048, 2048, 2048, 512);
      p.bias = l2b + l * 512;
      launch_gemm(p, 1, stream);
    }
    // 17. LN3: xbuf = LN(x2n + fbuf)
    ln512<<<dim3(512), dim3(256), 0, stream>>>(fbuf, x2n, 1, lng + (l * 3 + 2) * 512,
                                               lnbp + (l * 3 + 2) * 512, xbuf);
  }
  // final LN -> d_out
  ln512<<<dim3(512), dim3(256), 0, stream>>>(xbuf, nullptr, 0, fg, fbv, (float*)d_out);
}

// Round 3
// 797.290 us; speedup vs baseline: 3.3658x; 3.3658x over previous
//
#include <hip/hip_runtime.h>
#include <cstdint>

typedef __attribute__((ext_vector_type(8))) short short8;
typedef __attribute__((ext_vector_type(4))) float f32x4;
typedef __attribute__((ext_vector_type(4))) unsigned short us4;
typedef unsigned short u16;

static __device__ __forceinline__ u16 f2bf(float f) {
  union { float f; unsigned u; } x; x.f = f;
  return (u16)((x.u + 0x7FFFu + ((x.u >> 16) & 1u)) >> 16);
}

static __device__ __forceinline__ float wred_max(float v) {
#pragma unroll
  for (int o = 32; o > 0; o >>= 1) v = fmaxf(v, __shfl_xor(v, o, 64));
  return v;
}
static __device__ __forceinline__ float wred_sum(float v) {
#pragma unroll
  for (int o = 32; o > 0; o >>= 1) v += __shfl_xor(v, o, 64);
  return v;
}

static __device__ __forceinline__ void gload16(const void* g, void* l) {
  __builtin_amdgcn_global_load_lds(
      (const __attribute__((address_space(1))) unsigned int*)g,
      (__attribute__((address_space(3))) unsigned int*)l, 16, 0, 0);
}

// ---------------------------------------------------------------------------
// bf16 MFMA GEMM, all dims multiples of tile. A[M][K] bf16, Bt[N][K] bf16.
// C[z] addr = cbase + row*crs + col*ccs (fp32 or bf16).
// Staging: global_load_lds 16B with XOR-swizzled global source (involution
// matches swizzled ds_read_b128), BK=64, double-buffered 2-phase pipeline.
// ---------------------------------------------------------------------------
struct GemmP {
  const u16* A; const u16* B; void* C; const float* bias;
  int M, N, K, lda, ldb, crs, ccs;
  int azi, bzi, czi;
  long aso, asi, bso, bsi, cso, csi;
  float scale; int relu; int cbf16;
};

template<int ROWS>
static __device__ __forceinline__ void stage_t(const u16* g, int ld, u16* lds,
                                               int w, int lane) {
#pragma unroll
  for (int j = 0; j < ROWS / 32; ++j) {
    const int idx = w * (ROWS / 32) + j;
    const int r = idx * 8 + (lane >> 3);
    const int gc = ((lane & 7) ^ (r & 7)) * 8;  // swizzled 16B granule
    gload16(g + (long)r * ld + gc, lds + idx * 512);
  }
}

template<int BM, int BN>
__global__ __launch_bounds__(256, 4) void gemm_k(GemmP p) {
  constexpr int WTM = BM / 2, WTN = BN / 2;
  constexpr int FM = WTM / 16, FN = WTN / 16;
  __shared__ __align__(16) u16 Al[2][BM * 64];
  __shared__ __align__(16) u16 Bl[2][BN * 64];
  const int tid = threadIdx.x, lane = tid & 63, w = tid >> 6;
  const int wr = w >> 1, wc = w & 1, lr = lane & 15, lk4 = lane >> 4;
  const int z = blockIdx.z;
  const int tm = blockIdx.y * BM, tn = blockIdx.x * BN;
  const long ab = (long)(z / p.azi) * p.aso + (long)(z % p.azi) * p.asi + (long)tm * p.lda;
  const long bb = (long)(z / p.bzi) * p.bso + (long)(z % p.bzi) * p.bsi + (long)tn * p.ldb;
  const long cb = (long)(z / p.czi) * p.cso + (long)(z % p.czi) * p.csi;

  f32x4 acc[FM][FN];
#pragma unroll
  for (int i = 0; i < FM; ++i)
#pragma unroll
    for (int j = 0; j < FN; ++j) acc[i][j] = (f32x4)(0.0f);

  const u16* Ag = p.A + ab;
  const u16* Bg = p.B + bb;
  stage_t<BM>(Ag, p.lda, &Al[0][0], w, lane);
  stage_t<BN>(Bg, p.ldb, &Bl[0][0], w, lane);
  __syncthreads();

  const int nt = p.K >> 6;
  for (int t = 0; t < nt; ++t) {
    const int cur = t & 1;
    if (t + 1 < nt) {
      stage_t<BM>(Ag + (long)(t + 1) * 64, p.lda, &Al[cur ^ 1][0], w, lane);
      stage_t<BN>(Bg + (long)(t + 1) * 64, p.ldb, &Bl[cur ^ 1][0], w, lane);
    }
    short8 af[FM][2], bfv[FN][2];
#pragma unroll
    for (int ks = 0; ks < 2; ++ks) {
#pragma unroll
      for (int mi = 0; mi < FM; ++mi) {
        const int row = wr * WTM + mi * 16 + lr;
        const int off = row * 128 + ((ks * 4 + lk4) ^ (row & 7)) * 16;
        af[mi][ks] = *(const short8*)((const char*)&Al[cur][0] + off);
      }
#pragma unroll
      for (int ni = 0; ni < FN; ++ni) {
        const int row = wc * WTN + ni * 16 + lr;
        const int off = row * 128 + ((ks * 4 + lk4) ^ (row & 7)) * 16;
        bfv[ni][ks] = *(const short8*)((const char*)&Bl[cur][0] + off);
      }
    }
#pragma unroll
    for (int ks = 0; ks < 2; ++ks)
#pragma unroll
      for (int mi = 0; mi < FM; ++mi)
#pragma unroll
        for (int ni = 0; ni < FN; ++ni)
          acc[mi][ni] = __builtin_amdgcn_mfma_f32_16x16x32_bf16(af[mi][ks], bfv[ni][ks],
                                                                acc[mi][ni], 0, 0, 0);
    __syncthreads();
  }

  const int kg = lk4 * 4;
#pragma unroll
  for (int ni = 0; ni < FN; ++ni) {
    const int col = tn + wc * WTN + ni * 16 + lr;
    const float bv = p.bias ? p.bias[col] : 0.0f;
#pragma unroll
    for (int mi = 0; mi < FM; ++mi) {
      const int rb = tm + wr * WTM + mi * 16 + kg;
#pragma unroll
      for (int r = 0; r < 4; ++r) {
        float v = acc[mi][ni][r] * p.scale + bv;
        if (p.relu) v = fmaxf(v, 0.0f);
        const long ci = cb + (long)(rb + r) * p.crs + (long)col * p.ccs;
        if (p.cbf16) ((u16*)p.C)[ci] = f2bf(v);
        else ((float*)p.C)[ci] = v;
      }
    }
  }
}

template<int BM, int BN>
static inline void launchg(const GemmP& p, int nb, hipStream_t s) {
  dim3 g((unsigned)(p.N / BN), (unsigned)(p.M / BM), (unsigned)nb);
  hipLaunchKernelGGL((gemm_k<BM, BN>), g, dim3(256), 0, s, p);
}

// ---------------------------------------------------------------------------
// softmax over rows of 1024 fp32 -> bf16 (one wave per row)
// ---------------------------------------------------------------------------
__global__ __launch_bounds__(256) void softmax1024(const float* S, u16* P) {
  const int row = blockIdx.x * 4 + (threadIdx.x >> 6);
  const int lane = threadIdx.x & 63;
  const float* p = S + (long)row * 1024;
  u16* po = P + (long)row * 1024;
  f32x4 v[4];
#pragma unroll
  for (int i = 0; i < 4; ++i) v[i] = *(const f32x4*)&p[(i * 64 + lane) * 4];
  float mx = -3e38f;
#pragma unroll
  for (int i = 0; i < 4; ++i)
#pragma unroll
    for (int j = 0; j < 4; ++j) mx = fmaxf(mx, v[i][j]);
  mx = wred_max(mx);
  float sm = 0.f;
#pragma unroll
  for (int i = 0; i < 4; ++i)
#pragma unroll
    for (int j = 0; j < 4; ++j) { v[i][j] = __expf(v[i][j] - mx); sm += v[i][j]; }
  sm = wred_sum(sm);
  const float inv = 1.0f / sm;
#pragma unroll
  for (int i = 0; i < 4; ++i) {
    us4 ov;
#pragma unroll
    for (int j = 0; j < 4; ++j) ov[j] = f2bf(v[i][j] * inv);
    *(us4*)&po[(i * 64 + lane) * 4] = ov;
  }
}

// ---------------------------------------------------------------------------
// LayerNorm D=512; resmode: 0 none, 1 full, 2 broadcast[2][512]; optional bf16 out
// ---------------------------------------------------------------------------
__global__ __launch_bounds__(256) void ln512(const float* a, const float* res, int resmode,
                                             const float* g, const float* bt,
                                             float* out, u16* obf) {
  const int row = blockIdx.x * 4 + (threadIdx.x >> 6);
  const int lane = threadIdx.x & 63;
  const float* ar = a + (long)row * 512;
  f32x4 x[2];
#pragma unroll
  for (int i = 0; i < 2; ++i) {
    const int idx = (i * 64 + lane) * 4;
    x[i] = *(const f32x4*)&ar[idx];
    if (resmode == 1) x[i] += *(const f32x4*)&res[(long)row * 512 + idx];
    else if (resmode == 2) x[i] += *(const f32x4*)&res[(row & 1) * 512 + idx];
  }
  float s = 0.f;
#pragma unroll
  for (int i = 0; i < 2; ++i)
#pragma unroll
    for (int j = 0; j < 4; ++j) s += x[i][j];
  const float mean = wred_sum(s) * (1.0f / 512.0f);
  float vv = 0.f;
#pragma unroll
  for (int i = 0; i < 2; ++i)
#pragma unroll
    for (int j = 0; j < 4; ++j) { const float d = x[i][j] - mean; vv += d * d; }
  vv = wred_sum(vv) * (1.0f / 512.0f);
  const float rs = rsqrtf(vv + 1e-5f);
#pragma unroll
  for (int i = 0; i < 2; ++i) {
    const int idx = (i * 64 + lane) * 4;
    const f32x4 gv = *(const f32x4*)&g[idx];
    const f32x4 bv = *(const f32x4*)&bt[idx];
    f32x4 o;
#pragma unroll
    for (int j = 0; j < 4; ++j) o[j] = (x[i][j] - mean) * rs * gv[j] + bv[j];
    *(f32x4*)&out[(long)row * 512 + idx] = o;
    if (obf) {
      us4 ov;
#pragma unroll
      for (int j = 0; j < 4; ++j) ov[j] = f2bf(o[j]);
      *(us4*)&obf[(long)row * 512 + idx] = ov;
    }
  }
}

// ---------------------------------------------------------------------------
// fp32 -> bf16 converters (8 elems/thread, sizes multiples of 2048)
// ---------------------------------------------------------------------------
__global__ __launch_bounds__(256) void cvt1(const float* a, u16* o) {
  const long i = ((long)blockIdx.x * 256 + threadIdx.x) * 8;
  f32x4 a0 = *(const f32x4*)&a[i], a1 = *(const f32x4*)&a[i + 4];
  short8 ov;
#pragma unroll
  for (int c = 0; c < 4; ++c) { ov[c] = (short)f2bf(a0[c]); ov[c + 4] = (short)f2bf(a1[c]); }
  *(short8*)&o[i] = ov;
}

__global__ __launch_bounds__(256) void cvt2(const float* a, const float* b, u16* oa, u16* oab) {
  const long i = ((long)blockIdx.x * 256 + threadIdx.x) * 8;
  f32x4 a0 = *(const f32x4*)&a[i], a1 = *(const f32x4*)&a[i + 4];
  f32x4 b0 = *(const f32x4*)&b[i], b1 = *(const f32x4*)&b[i + 4];
  short8 o1, o2;
#pragma unroll
  for (int c = 0; c < 4; ++c) {
    o1[c] = (short)f2bf(a0[c]); o1[c + 4] = (short)f2bf(a1[c]);
    o2[c] = (short)f2bf(a0[c] + b0[c]); o2[c + 4] = (short)f2bf(a1[c] + b1[c]);
  }
  *(short8*)&oa[i] = o1; *(short8*)&oab[i] = o2;
}

// ---------------------------------------------------------------------------
// custom attention small kernels (fp32)
// ---------------------------------------------------------------------------
__global__ __launch_bounds__(512) void xsum1(const float* x1, const float* qpos, float* xp) {
  const int b = blockIdx.x >> 3, c = blockIdx.x & 7, d = threadIdx.x;
  float a = 0.f;
  for (int n = c * 128; n < c * 128 + 128; ++n) {
    const long i = ((long)(n * 2 + b)) * 512 + d;
    a += x1[i] + qpos[i];
  }
  xp[blockIdx.x * 512 + d] = a;
}

__global__ __launch_bounds__(512) void xsum2(const float* xp, float* xs) {
  const int b = blockIdx.x, d = threadIdx.x;
  float a = 0.f;
#pragma unroll
  for (int c = 0; c < 8; ++c) a += xp[(b * 8 + c) * 512 + d];
  xs[b * 512 + d] = a;
}

// qs[b][o] = W0[o,:]*xs[b] + 1024*b0[o]   (one wave per output)
__global__ __launch_bounds__(256) void qsv_k(const float* xs, const float* W0,
                                             const float* b0, float* qs) {
  const int b = blockIdx.y;
  const int o = blockIdx.x * 4 + (threadIdx.x >> 6);
  const int lane = threadIdx.x & 63;
  float a = 0.f;
#pragma unroll
  for (int i = 0; i < 8; ++i)
    a += W0[(long)o * 512 + lane + i * 64] * xs[b * 512 + lane + i * 64];
  a = wred_sum(a);
  if (lane == 0) qs[b * 512 + o] = a + 1024.0f * b0[o];
}

// s1[z][m] = 0.125 * sum_d qs[b][d*8+h] * kT[b][d*8+h][m]
__global__ __launch_bounds__(256) void s1_k(const float* qs, const float* kT, float* s1) {
  const int z = blockIdx.x, b = z >> 3, h = z & 7;
  const int m = blockIdx.y * 256 + threadIdx.x;
  float a = 0.f;
#pragma unroll 8
  for (int d = 0; d < 64; ++d) {
    const int ch = d * 8 + h;
    a += qs[b * 512 + ch] * kT[((long)b * 512 + ch) * 2048 + m];
  }
  s1[(long)z * 2048 + m] = 0.125f * a;
}

// per (z, nchunk of 8): softmax rows, accumulate mw[n]-weighted probs
__global__ __launch_bounds__(256) void pw_k(const float* kT, const float* s1,
                                            const float* mw, float* pwpart) {
  const int z = blockIdx.x & 15, c = blockIdx.x >> 4;
  const int b = z >> 3, h = z & 7;
  const int tid = threadIdx.x, lane = tid & 63, wid = tid >> 6;
  __shared__ float redm[4], reds[4];
  float s1v[8], pwa[8];
#pragma unroll
  for (int i = 0; i < 8; ++i) { s1v[i] = s1[(long)z * 2048 + tid + i * 256]; pwa[i] = 0.f; }
  for (int n = c * 8; n < c * 8 + 8; ++n) {
    const float* kr = kT + ((long)b * 512 + n * 8 + h) * 2048;
    float sv[8];
    float mx = -3e38f;
#pragma unroll
    for (int i = 0; i < 8; ++i) { sv[i] = kr[tid + i * 256] * s1v[i]; mx = fmaxf(mx, sv[i]); }
    mx = wred_max(mx);
    if (lane == 0) redm[wid] = mx;
    __syncthreads();
    mx = fmaxf(fmaxf(redm[0], redm[1]), fmaxf(redm[2], redm[3]));
    float sm = 0.f;
#pragma unroll
    for (int i = 0; i < 8; ++i) { sv[i] = __expf(sv[i] - mx); sm += sv[i]; }
    sm = wred_sum(sm);
    if (lane == 0) reds[wid] = sm;
    __syncthreads();
    sm = reds[0] + reds[1] + reds[2] + reds[3];
    const float wnl = mw[n] / sm;
#pragma unroll
    for (int i = 0; i < 8; ++i) pwa[i] += wnl * sv[i];
    __syncthreads();
  }
#pragma unroll
  for (int i = 0; i < 8; ++i)
    pwpart[((long)c * 16 + z) * 2048 + tid + i * 256] = pwa[i];
}

__global__ __launch_bounds__(256) void pw_red(const float* pwpart, float* pw) {
  const long i = (long)blockIdx.x * 256 + threadIdx.x;
  float a = 0.f;
#pragma unroll
  for (int c = 0; c < 8; ++c) a += pwpart[(long)c * 32768 + i];
  pw[i] = a;
}

// t2c[b][d*8+h] = sum_m vT[b][d*8+h][m]*pw[z][m] + mb
__global__ __launch_bounds__(256) void x2_k(const float* vT, const float* pw,
                                            const float* mb, float* t2c) {
  const int z = blockIdx.x, b = z >> 3, h = z & 7;
  const int tid = threadIdx.x, lane = tid & 63, wid = tid >> 6;
  const float* pr = pw + (long)z * 2048;
#pragma unroll
  for (int ci = 0; ci < 4; ++ci) {
    const int d = wid * 16 + blockIdx.y * 4 + ci, ch = d * 8 + h;
    const float* vr = vT + ((long)b * 512 + ch) * 2048;
    float acc = 0.f;
#pragma unroll 8
    for (int i = 0; i < 32; ++i) acc += vr[lane + i * 64] * pr[lane + i * 64];
    acc = wred_sum(acc);
    if (lane == 0) t2c[b * 512 + ch] = acc + mb[0];
  }
}

// ---------------------------------------------------------------------------
extern "C" void kernel_launch(void* const* d_in, const int* in_sizes, int n_in,
                              void* d_out, int out_size, void* d_ws, size_t ws_size,
                              hipStream_t stream) {
  (void)in_sizes; (void)n_in; (void)out_size; (void)ws_size;
  const float* tgt   = (const float*)d_in[0];
  const float* memry = (const float*)d_in[1];
  const float* qpos  = (const float*)d_in[2];
  const float* pos   = (const float*)d_in[3];
  const float* ipw   = (const float*)d_in[4];
  const float* ipb   = (const float*)d_in[5];
  const float* outw  = (const float*)d_in[6];
  const float* outb  = (const float*)d_in[7];
  const float* convw = (const float*)d_in[8];
  const float* convb = (const float*)d_in[9];
  const float* mlpw  = (const float*)d_in[10];
  const float* mlpb  = (const float*)d_in[11];
  const float* l1w   = (const float*)d_in[12];
  const float* l1b   = (const float*)d_in[13];
  const float* l2w   = (const float*)d_in[14];
  const float* l2b   = (const float*)d_in[15];
  const float* lng   = (const float*)d_in[16];
  const float* lnbp  = (const float*)d_in[17];
  const float* fg    = (const float*)d_in[18];
  const float* fbv   = (const float*)d_in[19];

  char* base = (char*)d_ws;
  const long MBy = 1 << 20;
  float* S     = (float*)(base + 0);          // 32MB (8 heads chunk)
  u16*   P     = (u16*)(base + 32 * MBy);     // 16MB
  u16*   qkb   = (u16*)(base + 48 * MBy);     // 4MB
  u16*   Vtb   = (u16*)(base + 52 * MBy);     // 2MB
  u16*   aob   = (u16*)(base + 54 * MBy);     // 2MB
  u16*   xb    = (u16*)(base + 56 * MBy);     // 2MB
  u16*   xqb   = (u16*)(base + 58 * MBy);     // 2MB
  u16*   memb  = (u16*)(base + 60 * MBy);     // 4MB
  u16*   mempb = (u16*)(base + 64 * MBy);     // 4MB
  u16*   x2nb  = (u16*)(base + 68 * MBy);     // 2MB
  u16*   hb    = (u16*)(base + 70 * MBy);     // 8MB
  float* t2    = (float*)(base + 78 * MBy);
  float* x1    = (float*)(base + 82 * MBy);
  float* x2n   = (float*)(base + 86 * MBy);
  float* fbuf  = (float*)(base + 90 * MBy);
  float* xbuf  = (float*)(base + 94 * MBy);
  float* kT    = (float*)(base + 98 * MBy);   // 8MB
  float* vT    = (float*)(base + 106 * MBy);  // 8MB
  u16* ipwb    = (u16*)(base + 114 * MBy);    // 6MB
  u16* outwb   = (u16*)(base + 120 * MBy);    // 2MB
  u16* convwb  = (u16*)(base + 122 * MBy);    // 6MB
  u16* l1wb    = (u16*)(base + 128 * MBy);    // 8MB
  u16* l2wb    = (u16*)(base + 136 * MBy);    // 8MB
  float* xpart = (float*)(base + 144 * MBy);            // 32KB
  float* xsumb = (float*)(base + 144 * MBy + 32 * 1024);
  float* qsb   = (float*)(base + 144 * MBy + 40 * 1024);
  float* s1b   = (float*)(base + 144 * MBy + 48 * 1024);   // 128KB
  float* pwpart= (float*)(base + 144 * MBy + 192 * 1024);  // 1MB
  float* pwb   = (float*)(base + 145 * MBy + 192 * 1024);  // 128KB
  float* t2c   = (float*)(base + 145 * MBy + 320 * 1024);

  // one-time weight / memory conversions
  cvt1<<<dim3(3145728 / 2048), dim3(256), 0, stream>>>(ipw, ipwb);
  cvt1<<<dim3(1048576 / 2048), dim3(256), 0, stream>>>(outw, outwb);
  cvt1<<<dim3(3145728 / 2048), dim3(256), 0, stream>>>(convw, convwb);
  cvt1<<<dim3(4194304 / 2048), dim3(256), 0, stream>>>(l1w, l1wb);
  cvt1<<<dim3(4194304 / 2048), dim3(256), 0, stream>>>(l2w, l2wb);
  cvt2<<<dim3(2097152 / 2048), dim3(256), 0, stream>>>(memry, pos, memb, mempb);

  for (int l = 0; l < 4; ++l) {
    const float* xin = l ? xbuf : tgt;
    cvt2<<<dim3(512), dim3(256), 0, stream>>>(xin, qpos, xb, xqb);

    GemmP p{};
    p.azi = p.bzi = p.czi = 1; p.scale = 1.0f;
    // qk projection: (x+qpos) -> qkb [2048][1024] bf16
    p.A = xqb; p.lda = 512; p.B = ipwb + (long)l * 786432; p.ldb = 512;
    p.C = qkb; p.crs = 1024; p.ccs = 1; p.cbf16 = 1;
    p.bias = ipb + (long)l * 1536;
    p.M = 2048; p.N = 1024; p.K = 512;
    p.aso = p.asi = p.bso = p.bsi = p.cso = p.csi = 0;
    launchg<64, 64>(p, 1, stream);
    // v projection -> Vtb[b][ch][n] bf16
    p = GemmP{}; p.azi = p.bzi = p.czi = 1; p.scale = 1.0f;
    p.A = xb; p.lda = 1024; p.aso = 512;
    p.B = ipwb + (long)l * 786432 + 524288; p.ldb = 512;
    p.C = Vtb; p.crs = 1; p.ccs = 1024; p.cso = 524288; p.cbf16 = 1;
    p.bias = ipb + (long)l * 1536 + 1024;
    p.M = 1024; p.N = 512; p.K = 512;
    launchg<32, 64>(p, 2, stream);

    // attention, chunked by batch (8 heads each)
    for (int c = 0; c < 2; ++c) {
      GemmP q{}; q.czi = 1; q.scale = 0.125f;
      q.A = qkb + c * 1024; q.lda = 2048; q.azi = 8; q.asi = 64;
      q.B = qkb + c * 1024 + 512; q.ldb = 2048; q.bzi = 8; q.bsi = 64;
      q.C = S; q.crs = 1024; q.ccs = 1; q.cso = 1048576; q.cbf16 = 0;
      q.M = 1024; q.N = 1024; q.K = 64;
      launchg<64, 64>(q, 8, stream);
      softmax1024<<<dim3(2048), dim3(256), 0, stream>>>(S, P);
      GemmP v{}; v.scale = 1.0f;
      v.A = P; v.lda = 1024; v.azi = 1; v.aso = 1048576;
      v.B = Vtb + (long)c * 524288; v.ldb = 1024; v.bzi = 8; v.bsi = 65536;
      v.C = aob + c * 512; v.czi = 8; v.csi = 64; v.crs = 1024; v.ccs = 1; v.cbf16 = 1;
      v.M = 1024; v.N = 64; v.K = 1024;
      launchg<32, 32>(v, 8, stream);
    }

    // out projection -> t2 fp32
    p = GemmP{}; p.azi = p.bzi = p.czi = 1; p.scale = 1.0f;
    p.A = aob; p.lda = 512; p.B = outwb + (long)l * 262144; p.ldb = 512;
    p.C = t2; p.crs = 512; p.ccs = 1; p.cbf16 = 0;
    p.bias = outb + l * 512;
    p.M = 2048; p.N = 512; p.K = 512;
    launchg<32, 64>(p, 1, stream);

    ln512<<<dim3(512), dim3(256), 0, stream>>>(t2, xin, 1, lng + (l * 3) * 512,
                                               lnbp + (l * 3) * 512, x1, nullptr);

    // conv k projection (memory+pos) -> kT fp32 [b][ch][m]
    p = GemmP{}; p.azi = p.bzi = p.czi = 1; p.scale = 1.0f;
    p.A = mempb; p.lda = 1024; p.aso = 512;
    p.B = convwb + ((long)l * 3 + 1) * 262144; p.ldb = 512;
    p.C = kT; p.crs = 1; p.ccs = 2048; p.cso = 1048576; p.cbf16 = 0;
    p.bias = convb + (l * 3 + 1) * 512;
    p.M = 2048; p.N = 512; p.K = 512;
    launchg<64, 64>(p, 2, stream);
    // conv v projection (memory) -> vT
    p.A = memb; p.B = convwb + ((long)l * 3 + 2) * 262144;
    p.C = vT; p.bias = convb + (l * 3 + 2) * 512;
    launchg<64, 64>(p, 2, stream);

    // custom attention
    xsum1<<<dim3(16), dim3(512), 0, stream>>>(x1, qpos, xpart);
    xsum2<<<dim3(2), dim3(512), 0, stream>>>(xpart, xsumb);
    qsv_k<<<dim3(128, 2), dim3(256), 0, stream>>>(xsumb, convw + ((long)l * 3) * 262144,
                                                  convb + (l * 3) * 512, qsb);
    s1_k<<<dim3(16, 8), dim3(256), 0, stream>>>(qsb, kT, s1b);
    pw_k<<<dim3(128), dim3(256), 0, stream>>>(kT, s1b, mlpw + l * 64, pwpart);
    pw_red<<<dim3(128), dim3(256), 0, stream>>>(pwpart, pwb);
    x2_k<<<dim3(16, 4), dim3(256), 0, stream>>>(vT, pwb, mlpb + l, t2c);

    ln512<<<dim3(512), dim3(256), 0, stream>>>(x1, t2c, 2, lng + (l * 3 + 1) * 512,
                                               lnbp + (l * 3 + 1) * 512, x2n, x2nb);

    // FFN
    p = GemmP{}; p.azi = p.bzi = p.czi = 1; p.scale = 1.0f;
    p.A = x2nb; p.lda = 512; p.B = l1wb + (long)l * 1048576; p.ldb = 512;
    p.C = hb; p.crs = 2048; p.ccs = 1; p.cbf16 = 1; p.relu = 1;
    p.bias = l1b + l * 2048;
    p.M = 2048; p.N = 2048; p.K = 512;
    launchg<64, 64>(p, 1, stream);

    p = GemmP{}; p.azi = p.bzi = p.czi = 1; p.scale = 1.0f;
    p.A = hb; p.lda = 2048; p.B = l2wb + (long)l * 1048576; p.ldb = 2048;
    p.C = fbuf; p.crs = 512; p.ccs = 1; p.cbf16 = 0;
    p.bias = l2b + l * 512;
    p.M = 2048; p.N = 512; p.K = 2048;
    launchg<32, 64>(p, 1, stream);

    ln512<<<dim3(512), dim3(256), 0, stream>>>(fbuf, x2n, 1, lng + (l * 3 + 2) * 512,
                                               lnbp + (l * 3 + 2) * 512, xbuf, nullptr);
  }
  ln512<<<dim3(512), dim3(256), 0, stream>>>(xbuf, nullptr, 0, fg, fbv, (float*)d_out, nullptr);
}

// Round 4
// 654.047 us; speedup vs baseline: 4.1029x; 1.2190x over previous
//
#include <hip/hip_runtime.h>
#include <cstdint>

typedef __attribute__((ext_vector_type(8))) short short8;
typedef __attribute__((ext_vector_type(4))) float f32x4;
typedef __attribute__((ext_vector_type(4))) unsigned short us4;
typedef unsigned short u16;

static __device__ __forceinline__ u16 f2bf(float f) {
  union { float f; unsigned u; } x; x.f = f;
  return (u16)((x.u + 0x7FFFu + ((x.u >> 16) & 1u)) >> 16);
}

static __device__ __forceinline__ float wred_max(float v) {
#pragma unroll
  for (int o = 32; o > 0; o >>= 1) v = fmaxf(v, __shfl_xor(v, o, 64));
  return v;
}
static __device__ __forceinline__ float wred_sum(float v) {
#pragma unroll
  for (int o = 32; o > 0; o >>= 1) v += __shfl_xor(v, o, 64);
  return v;
}

static __device__ __forceinline__ void gload16(const void* g, void* l) {
  __builtin_amdgcn_global_load_lds(
      (const __attribute__((address_space(1))) unsigned int*)g,
      (__attribute__((address_space(3))) unsigned int*)l, 16, 0, 0);
}

// ---------------------------------------------------------------------------
// bf16 MFMA GEMM (dims multiples of tile). A[M][K] bf16, Bt[N][K] bf16.
// ---------------------------------------------------------------------------
struct GemmP {
  const u16* A; const u16* B; void* C; const float* bias;
  int M, N, K, lda, ldb, crs, ccs;
  int azi, bzi, czi, biasdz;
  long aso, asi, bso, bsi, cso, csi, biassz;
  float scale; int relu; int cbf16;
};

template<int ROWS>
static __device__ __forceinline__ void stage_t(const u16* g, int ld, u16* lds,
                                               int w, int lane) {
#pragma unroll
  for (int j = 0; j < ROWS / 32; ++j) {
    const int idx = w * (ROWS / 32) + j;
    const int r = idx * 8 + (lane >> 3);
    const int gc = ((lane & 7) ^ (r & 7)) * 8;  // swizzled 16B granule
    gload16(g + (long)r * ld + gc, lds + idx * 512);
  }
}

template<int BM, int BN>
__global__ __launch_bounds__(256, 4) void gemm_k(GemmP p) {
  constexpr int WTM = BM / 2, WTN = BN / 2;
  constexpr int FM = WTM / 16, FN = WTN / 16;
  __shared__ __align__(16) u16 Al[2][BM * 64];
  __shared__ __align__(16) u16 Bl[2][BN * 64];
  const int tid = threadIdx.x, lane = tid & 63, w = tid >> 6;
  const int wr = w >> 1, wc = w & 1, lr = lane & 15, lk4 = lane >> 4;
  const int z = blockIdx.z;
  const int tm = blockIdx.y * BM, tn = blockIdx.x * BN;
  const long ab = (long)(z / p.azi) * p.aso + (long)(z % p.azi) * p.asi + (long)tm * p.lda;
  const long bb = (long)(z / p.bzi) * p.bso + (long)(z % p.bzi) * p.bsi + (long)tn * p.ldb;
  const long cb = (long)(z / p.czi) * p.cso + (long)(z % p.czi) * p.csi;
  const long boff = p.biasdz ? (long)(z / p.biasdz) * p.biassz : 0;

  f32x4 acc[FM][FN];
#pragma unroll
  for (int i = 0; i < FM; ++i)
#pragma unroll
    for (int j = 0; j < FN; ++j) acc[i][j] = (f32x4)(0.0f);

  const u16* Ag = p.A + ab;
  const u16* Bg = p.B + bb;
  stage_t<BM>(Ag, p.lda, &Al[0][0], w, lane);
  stage_t<BN>(Bg, p.ldb, &Bl[0][0], w, lane);
  __syncthreads();

  const int nt = p.K >> 6;
  for (int t = 0; t < nt; ++t) {
    const int cur = t & 1;
    if (t + 1 < nt) {
      stage_t<BM>(Ag + (long)(t + 1) * 64, p.lda, &Al[cur ^ 1][0], w, lane);
      stage_t<BN>(Bg + (long)(t + 1) * 64, p.ldb, &Bl[cur ^ 1][0], w, lane);
    }
    short8 af[FM][2], bfv[FN][2];
#pragma unroll
    for (int ks = 0; ks < 2; ++ks) {
#pragma unroll
      for (int mi = 0; mi < FM; ++mi) {
        const int row = wr * WTM + mi * 16 + lr;
        const int off = row * 128 + ((ks * 4 + lk4) ^ (row & 7)) * 16;
        af[mi][ks] = *(const short8*)((const char*)&Al[cur][0] + off);
      }
#pragma unroll
      for (int ni = 0; ni < FN; ++ni) {
        const int row = wc * WTN + ni * 16 + lr;
        const int off = row * 128 + ((ks * 4 + lk4) ^ (row & 7)) * 16;
        bfv[ni][ks] = *(const short8*)((const char*)&Bl[cur][0] + off);
      }
    }
#pragma unroll
    for (int ks = 0; ks < 2; ++ks)
#pragma unroll
      for (int mi = 0; mi < FM; ++mi)
#pragma unroll
        for (int ni = 0; ni < FN; ++ni)
          acc[mi][ni] = __builtin_amdgcn_mfma_f32_16x16x32_bf16(af[mi][ks], bfv[ni][ks],
                                                                acc[mi][ni], 0, 0, 0);
    __syncthreads();
  }

  const int kg = lk4 * 4;
#pragma unroll
  for (int ni = 0; ni < FN; ++ni) {
    const int col = tn + wc * WTN + ni * 16 + lr;
    const float bv = p.bias ? p.bias[boff + col] : 0.0f;
#pragma unroll
    for (int mi = 0; mi < FM; ++mi) {
      const int rb = tm + wr * WTM + mi * 16 + kg;
#pragma unroll
      for (int r = 0; r < 4; ++r) {
        float v = acc[mi][ni][r] * p.scale + bv;
        if (p.relu) v = fmaxf(v, 0.0f);
        const long ci = cb + (long)(rb + r) * p.crs + (long)col * p.ccs;
        if (p.cbf16) ((u16*)p.C)[ci] = f2bf(v);
        else ((float*)p.C)[ci] = v;
      }
    }
  }
}

template<int BM, int BN>
static inline void launchg(const GemmP& p, int nb, hipStream_t s) {
  dim3 g((unsigned)(p.N / BN), (unsigned)(p.M / BM), (unsigned)nb);
  hipLaunchKernelGGL((gemm_k<BM, BN>), g, dim3(256), 0, s, p);
}

// ---------------------------------------------------------------------------
// Fused flash attention. Grid (16 zh, 16 qtiles), 256 threads (4 waves).
// Per block: one (b,h), 64 queries (16/wave). K/V double-buffered in LDS via
// swizzled global_load_lds; swapped-operand QK^T; online softmax; P via
// per-wave LDS; PV accumulates O^T. qkb[2048][1024] (q cols 0-511, k 512-1023),
// Vtb[b][ch][n], out aob[2048][512] bf16.
// ---------------------------------------------------------------------------
__global__ __launch_bounds__(256) void flash_attn(const u16* qkb, const u16* Vtb, u16* aob) {
  const int zh = blockIdx.x, b = zh >> 3, h = zh & 7;
  const int qt = blockIdx.y;
  const int tid = threadIdx.x, lane = tid & 63, w = tid >> 6;
  const int lr = lane & 15, g = lane >> 4;

  __shared__ __align__(16) u16 Kl[2][64 * 64];
  __shared__ __align__(16) u16 Vl[2][64 * 64];
  __shared__ __align__(16) u16 Pl[4][16 * 64];

  const int nrow = qt * 64 + w * 16 + lr;
  const long qbase = ((long)(nrow * 2 + b)) * 1024 + h * 64;
  const short8 q0 = *(const short8*)&qkb[qbase + g * 8];
  const short8 q1 = *(const short8*)&qkb[qbase + 32 + g * 8];

  f32x4 acc_o[4];
#pragma unroll
  for (int i = 0; i < 4; ++i) acc_o[i] = (f32x4)(0.0f);
  float m_run = -3e38f, l_run = 0.0f;

  auto stage = [&](int buf, int t) {
    const int m0 = t * 64;
#pragma unroll
    for (int j = 0; j < 2; ++j) {
      const int c = w * 2 + j;
      const int row = c * 8 + (lane >> 3);
      const int src = (lane & 7) ^ (row & 7);
      gload16(qkb + ((long)((m0 + row) * 2 + b)) * 1024 + 512 + h * 64 + src * 8,
              &Kl[buf][c * 512]);
      gload16(Vtb + (long)b * 524288 + ((long)(h * 64 + row)) * 1024 + m0 + src * 8,
              &Vl[buf][c * 512]);
    }
  };

  stage(0, 0);
  __syncthreads();

  for (int t = 0; t < 16; ++t) {
    const int cur = t & 1;
    if (t < 15) stage(cur ^ 1, t + 1);

    // QK^T (swapped): rows=keys, cols=queries
    f32x4 s_acc[4];
#pragma unroll
    for (int ks = 0; ks < 4; ++ks) {
      const int krow = ks * 16 + lr;
      const short8 k0 = *(const short8*)&Kl[cur][krow * 64 + ((g ^ (krow & 7)) * 8)];
      const short8 k1 = *(const short8*)&Kl[cur][krow * 64 + (((4 + g) ^ (krow & 7)) * 8)];
      f32x4 z4 = (f32x4)(0.0f);
      z4 = __builtin_amdgcn_mfma_f32_16x16x32_bf16(k0, q0, z4, 0, 0, 0);
      z4 = __builtin_amdgcn_mfma_f32_16x16x32_bf16(k1, q1, z4, 0, 0, 0);
      s_acc[ks] = z4;
    }

    // online softmax over this tile's 64 keys (per query col = lane&15)
    float mx = -3e38f;
#pragma unroll
    for (int ks = 0; ks < 4; ++ks)
#pragma unroll
      for (int r = 0; r < 4; ++r) mx = fmaxf(mx, s_acc[ks][r]);
    mx = fmaxf(mx, __shfl_xor(mx, 16, 64));
    mx = fmaxf(mx, __shfl_xor(mx, 32, 64));
    mx *= 0.125f;
    const float m_new = fmaxf(m_run, mx);
    const float alpha = __expf(m_run - m_new);
    float psum = 0.0f;
    u16 pb[4][4];
#pragma unroll
    for (int ks = 0; ks < 4; ++ks)
#pragma unroll
      for (int r = 0; r < 4; ++r) {
        const float pv = __expf(s_acc[ks][r] * 0.125f - m_new);
        psum += pv;
        pb[ks][r] = f2bf(pv);
      }
    psum += __shfl_xor(psum, 16, 64);
    psum += __shfl_xor(psum, 32, 64);
    l_run = l_run * alpha + psum;
    m_run = m_new;
#pragma unroll
    for (int i = 0; i < 4; ++i) acc_o[i] *= alpha;

    // write P^T tile (16 n x 64 m) to per-wave LDS, granule-swizzled
#pragma unroll
    for (int ks = 0; ks < 4; ++ks)
#pragma unroll
      for (int r = 0; r < 4; ++r) {
        const int m = ks * 16 + g * 4 + r;
        Pl[w][lr * 64 + (((m >> 3) ^ (lr & 7)) * 8) + (m & 7)] = pb[ks][r];
      }

    // PV: O^T[d][n] += Vt[d][m] * P^T[m][n]
#pragma unroll
    for (int mh = 0; mh < 2; ++mh) {
      const short8 pt = *(const short8*)&Pl[w][lr * 64 + (((mh * 4 + g) ^ (lr & 7)) * 8)];
#pragma unroll
      for (int ds = 0; ds < 4; ++ds) {
        const int drow = ds * 16 + lr;
        const short8 vt = *(const short8*)&Vl[cur][drow * 64 + (((mh * 4 + g) ^ (drow & 7)) * 8)];
        acc_o[ds] = __builtin_amdgcn_mfma_f32_16x16x32_bf16(vt, pt, acc_o[ds], 0, 0, 0);
      }
    }
    __syncthreads();
  }

  const float invl = 1.0f / l_run;
#pragma unroll
  for (int ds = 0; ds < 4; ++ds)
#pragma unroll
    for (int r = 0; r < 4; ++r) {
      const int d = ds * 16 + g * 4 + r;
      aob[((long)(nrow * 2 + b)) * 512 + h * 64 + d] = f2bf(acc_o[ds][r] * invl);
    }
}

// ---------------------------------------------------------------------------
// LayerNorm D=512; resmode 0/1/2; optional bf16 out; optional bf16(out+add2)
// ---------------------------------------------------------------------------
__global__ __launch_bounds__(256) void ln512(const float* a, const float* res, int resmode,
                                             const float* g, const float* bt,
                                             float* out, u16* obf,
                                             const float* add2, u16* obf2) {
  const int row = blockIdx.x * 4 + (threadIdx.x >> 6);
  const int lane = threadIdx.x & 63;
  const float* ar = a + (long)row * 512;
  f32x4 x[2];
#pragma unroll
  for (int i = 0; i < 2; ++i) {
    const int idx = (i * 64 + lane) * 4;
    x[i] = *(const f32x4*)&ar[idx];
    if (resmode == 1) x[i] += *(const f32x4*)&res[(long)row * 512 + idx];
    else if (resmode == 2) x[i] += *(const f32x4*)&res[(row & 1) * 512 + idx];
  }
  float s = 0.f;
#pragma unroll
  for (int i = 0; i < 2; ++i)
#pragma unroll
    for (int j = 0; j < 4; ++j) s += x[i][j];
  const float mean = wred_sum(s) * (1.0f / 512.0f);
  float vv = 0.f;
#pragma unroll
  for (int i = 0; i < 2; ++i)
#pragma unroll
    for (int j = 0; j < 4; ++j) { const float d = x[i][j] - mean; vv += d * d; }
  vv = wred_sum(vv) * (1.0f / 512.0f);
  const float rs = rsqrtf(vv + 1e-5f);
#pragma unroll
  for (int i = 0; i < 2; ++i) {
    const int idx = (i * 64 + lane) * 4;
    const f32x4 gv = *(const f32x4*)&g[idx];
    const f32x4 bv = *(const f32x4*)&bt[idx];
    f32x4 o;
#pragma unroll
    for (int j = 0; j < 4; ++j) o[j] = (x[i][j] - mean) * rs * gv[j] + bv[j];
    *(f32x4*)&out[(long)row * 512 + idx] = o;
    if (obf) {
      us4 ov;
#pragma unroll
      for (int j = 0; j < 4; ++j) ov[j] = f2bf(o[j]);
      *(us4*)&obf[(long)row * 512 + idx] = ov;
    }
    if (obf2) {
      const f32x4 a2 = *(const f32x4*)&add2[(long)row * 512 + idx];
      us4 ov;
#pragma unroll
      for (int j = 0; j < 4; ++j) ov[j] = f2bf(o[j] + a2[j]);
      *(us4*)&obf2[(long)row * 512 + idx] = ov;
    }
  }
}

// ---------------------------------------------------------------------------
// converters
// ---------------------------------------------------------------------------
struct CvtSeg { const float* s; u16* d; int nblk; };
struct Cvt5 { CvtSeg seg[5]; };
__global__ __launch_bounds__(256) void cvt_multi(Cvt5 c) {
  int b = blockIdx.x, si = 0;
  while (si < 4 && b >= c.seg[si].nblk) { b -= c.seg[si].nblk; ++si; }
  const float* a = c.seg[si].s;
  u16* o = c.seg[si].d;
  const long i = ((long)b * 256 + threadIdx.x) * 8;
  f32x4 a0 = *(const f32x4*)&a[i], a1 = *(const f32x4*)&a[i + 4];
  short8 ov;
#pragma unroll
  for (int k = 0; k < 4; ++k) { ov[k] = (short)f2bf(a0[k]); ov[k + 4] = (short)f2bf(a1[k]); }
  *(short8*)&o[i] = ov;
}

__global__ __launch_bounds__(256) void cvt2(const float* a, const float* b, u16* oa, u16* oab) {
  const long i = ((long)blockIdx.x * 256 + threadIdx.x) * 8;
  f32x4 a0 = *(const f32x4*)&a[i], a1 = *(const f32x4*)&a[i + 4];
  f32x4 b0 = *(const f32x4*)&b[i], b1 = *(const f32x4*)&b[i + 4];
  short8 o1, o2;
#pragma unroll
  for (int c = 0; c < 4; ++c) {
    o1[c] = (short)f2bf(a0[c]); o1[c + 4] = (short)f2bf(a1[c]);
    o2[c] = (short)f2bf(a0[c] + b0[c]); o2[c + 4] = (short)f2bf(a1[c] + b1[c]);
  }
  *(short8*)&oa[i] = o1; *(short8*)&oab[i] = o2;
}

// ---------------------------------------------------------------------------
// custom attention small kernels (fp32)
// ---------------------------------------------------------------------------
__global__ __launch_bounds__(512) void xsum1(const float* x1, const float* qpos, float* xp) {
  const int b = blockIdx.x >> 4, c = blockIdx.x & 15, d = threadIdx.x;
  float a = 0.f;
  for (int n = c * 64; n < c * 64 + 64; ++n) {
    const long i = ((long)(n * 2 + b)) * 512 + d;
    a += x1[i] + qpos[i];
  }
  xp[blockIdx.x * 512 + d] = a;
}

__global__ __launch_bounds__(512) void xsum2(const float* xp, float* xs) {
  const int b = blockIdx.x, d = threadIdx.x;
  float a = 0.f;
#pragma unroll
  for (int c = 0; c < 16; ++c) a += xp[(b * 16 + c) * 512 + d];
  xs[b * 512 + d] = a;
}

// qs (in LDS) then s1[z][m] = 0.125 * sum_d qs[d] * kT[b][d*8+h][m]
__global__ __launch_bounds__(256) void s1_k(const float* xs, const float* W0, const float* b0,
                                            const float* kT, float* s1) {
  const int z = blockIdx.x, b = z >> 3, h = z & 7;
  const int tid = threadIdx.x;
  __shared__ float part[4][64];
  __shared__ float qs[64];
  const int d = tid & 63, qd = tid >> 6;
  const int ch = d * 8 + h;
  float pp = 0.f;
  const float* wrp = W0 + (long)ch * 512 + qd * 128;
  const float* xrp = xs + b * 512 + qd * 128;
#pragma unroll 8
  for (int i = 0; i < 128; ++i) pp += wrp[i] * xrp[i];
  part[qd][d] = pp;
  __syncthreads();
  if (tid < 64)
    qs[tid] = part[0][tid] + part[1][tid] + part[2][tid] + part[3][tid]
              + 1024.0f * b0[tid * 8 + h];
  __syncthreads();
  const int m = blockIdx.y * 256 + tid;
  float a = 0.f;
#pragma unroll 8
  for (int dd = 0; dd < 64; ++dd)
    a += qs[dd] * kT[((long)b * 512 + dd * 8 + h) * 2048 + m];
  s1[(long)z * 2048 + m] = 0.125f * a;
}

// per (z, nchunk of 8): softmax rows, accumulate mw[n]-weighted probs -> partials
__global__ __launch_bounds__(256) void pw_k(const float* kT, const float* s1,
                                            const float* mw, float* pwpart) {
  const int z = blockIdx.x & 15, c = blockIdx.x >> 4;
  const int b = z >> 3, h = z & 7;
  const int tid = threadIdx.x, lane = tid & 63, wid = tid >> 6;
  __shared__ float redm[4], reds[4];
  float s1v[8], pwa[8];
#pragma unroll
  for (int i = 0; i < 8; ++i) { s1v[i] = s1[(long)z * 2048 + tid + i * 256]; pwa[i] = 0.f; }
  for (int n = c * 8; n < c * 8 + 8; ++n) {
    const float* kr = kT + ((long)b * 512 + n * 8 + h) * 2048;
    float sv[8];
    float mx = -3e38f;
#pragma unroll
    for (int i = 0; i < 8; ++i) { sv[i] = kr[tid + i * 256] * s1v[i]; mx = fmaxf(mx, sv[i]); }
    mx = wred_max(mx);
    if (lane == 0) redm[wid] = mx;
    __syncthreads();
    mx = fmaxf(fmaxf(redm[0], redm[1]), fmaxf(redm[2], redm[3]));
    float sm = 0.f;
#pragma unroll
    for (int i = 0; i < 8; ++i) { sv[i] = __expf(sv[i] - mx); sm += sv[i]; }
    sm = wred_sum(sm);
    if (lane == 0) reds[wid] = sm;
    __syncthreads();
    sm = reds[0] + reds[1] + reds[2] + reds[3];
    const float wnl = mw[n] / sm;
#pragma unroll
    for (int i = 0; i < 8; ++i) pwa[i] += wnl * sv[i];
    __syncthreads();
  }
#pragma unroll
  for (int i = 0; i < 8; ++i)
    pwpart[((long)c * 16 + z) * 2048 + tid + i * 256] = pwa[i];
}

// t2c[b][d*8+h] = sum_m vT[b][d*8+h][m] * (sum_c pwpart[c][z][m]) + mb
__global__ __launch_bounds__(256) void x2_k(const float* vT, const float* pwpart,
                                            const float* mb, float* t2c) {
  const int z = blockIdx.x, b = z >> 3, h = z & 7;
  const int tid = threadIdx.x, lane = tid & 63, wid = tid >> 6;
  float pwv[32];
#pragma unroll 4
  for (int i = 0; i < 32; ++i) {
    const int m = lane + i * 64;
    float s = 0.f;
#pragma unroll
    for (int c = 0; c < 8; ++c) s += pwpart[((long)c * 16 + z) * 2048 + m];
    pwv[i] = s;
  }
#pragma unroll
  for (int ci = 0; ci < 4; ++ci) {
    const int d = wid * 16 + blockIdx.y * 4 + ci, ch = d * 8 + h;
    const float* vr = vT + ((long)b * 512 + ch) * 2048;
    float acc = 0.f;
#pragma unroll 8
    for (int i = 0; i < 32; ++i) acc += vr[lane + i * 64] * pwv[i];
    acc = wred_sum(acc);
    if (lane == 0) t2c[b * 512 + ch] = acc + mb[0];
  }
}

// ---------------------------------------------------------------------------
extern "C" void kernel_launch(void* const* d_in, const int* in_sizes, int n_in,
                              void* d_out, int out_size, void* d_ws, size_t ws_size,
                              hipStream_t stream) {
  (void)in_sizes; (void)n_in; (void)out_size; (void)ws_size;
  const float* tgt   = (const float*)d_in[0];
  const float* memry = (const float*)d_in[1];
  const float* qpos  = (const float*)d_in[2];
  const float* pos   = (const float*)d_in[3];
  const float* ipw   = (const float*)d_in[4];
  const float* ipb   = (const float*)d_in[5];
  const float* outw  = (const float*)d_in[6];
  const float* outb  = (const float*)d_in[7];
  const float* convw = (const float*)d_in[8];
  const float* convb = (const float*)d_in[9];
  const float* mlpw  = (const float*)d_in[10];
  const float* mlpb  = (const float*)d_in[11];
  const float* l1w   = (const float*)d_in[12];
  const float* l1b   = (const float*)d_in[13];
  const float* l2w   = (const float*)d_in[14];
  const float* l2b   = (const float*)d_in[15];
  const float* lng   = (const float*)d_in[16];
  const float* lnbp  = (const float*)d_in[17];
  const float* fg    = (const float*)d_in[18];
  const float* fbv   = (const float*)d_in[19];

  char* base = (char*)d_ws;
  const long MBy = 1 << 20;
  u16*   qkb   = (u16*)(base + 0);            // 4MB
  u16*   Vtb   = (u16*)(base + 4 * MBy);      // 2MB
  u16*   aob   = (u16*)(base + 6 * MBy);      // 2MB
  u16*   xb    = (u16*)(base + 8 * MBy);      // 2MB
  u16*   xqb   = (u16*)(base + 10 * MBy);     // 2MB
  u16*   mempb = (u16*)(base + 12 * MBy);     // 4MB  (memory+pos bf16)
  u16*   memb  = (u16*)(base + 16 * MBy);     // 4MB  (memory bf16) -- adjacent!
  u16*   x2nb  = (u16*)(base + 20 * MBy);     // 2MB
  u16*   hb    = (u16*)(base + 22 * MBy);     // 8MB
  float* t2    = (float*)(base + 30 * MBy);   // 4MB
  float* x1    = (float*)(base + 34 * MBy);   // 4MB
  float* x2n   = (float*)(base + 38 * MBy);   // 4MB
  float* fbuf  = (float*)(base + 42 * MBy);   // 4MB
  float* xbuf  = (float*)(base + 46 * MBy);   // 4MB
  float* kT    = (float*)(base + 50 * MBy);   // 8MB [2][512][2048]
  float* vT    = (float*)(base + 58 * MBy);   // 8MB -- adjacent to kT!
  u16*   ipwb  = (u16*)(base + 66 * MBy);     // 6MB
  u16*   outwb = (u16*)(base + 72 * MBy);     // 2MB
  u16*   convwb= (u16*)(base + 74 * MBy);     // 6MB
  u16*   l1wb  = (u16*)(base + 80 * MBy);     // 8MB
  u16*   l2wb  = (u16*)(base + 88 * MBy);     // 8MB
  float* xpart = (float*)(base + 96 * MBy);              // 64KB
  float* xsumb = (float*)(base + 96 * MBy + 64 * 1024);  // 4KB
  float* s1b   = (float*)(base + 96 * MBy + 72 * 1024);  // 128KB
  float* pwpart= (float*)(base + 96 * MBy + 200 * 1024); // 1MB
  float* t2c   = (float*)(base + 97 * MBy + 200 * 1024); // 4KB

  // one-time conversions (weights via single segmented kernel)
  {
    Cvt5 c;
    c.seg[0] = { ipw,   ipwb,  1536 };
    c.seg[1] = { outw,  outwb,  512 };
    c.seg[2] = { convw, convwb, 1536 };
    c.seg[3] = { l1w,   l1wb,  2048 };
    c.seg[4] = { l2w,   l2wb,  2048 };
    cvt_multi<<<dim3(7680), dim3(256), 0, stream>>>(c);
  }
  cvt2<<<dim3(1024), dim3(256), 0, stream>>>(memry, pos, memb, mempb);
  cvt2<<<dim3(512), dim3(256), 0, stream>>>(tgt, qpos, xb, xqb);

  for (int l = 0; l < 4; ++l) {
    const float* xin = l ? xbuf : tgt;

    GemmP p{};
    // qk projection: (x+qpos) @ [wq;wk]^T -> qkb [2048][1024] bf16
    p.azi = p.bzi = p.czi = 1; p.scale = 1.0f;
    p.A = xqb; p.lda = 512; p.B = ipwb + (long)l * 786432; p.ldb = 512;
    p.C = qkb; p.crs = 1024; p.ccs = 1; p.cbf16 = 1;
    p.bias = ipb + (long)l * 1536;
    p.M = 2048; p.N = 1024; p.K = 512;
    launchg<64, 64>(p, 1, stream);

    // v projection -> Vtb[b][ch][n] bf16 (transposed C), batched over b
    p = GemmP{}; p.azi = p.bzi = p.czi = 1; p.scale = 1.0f;
    p.A = xb; p.lda = 1024; p.aso = 512;
    p.B = ipwb + (long)l * 786432 + 524288; p.ldb = 512;
    p.C = Vtb; p.crs = 1; p.ccs = 1024; p.cso = 524288; p.cbf16 = 1;
    p.bias = ipb + (long)l * 1536 + 1024;
    p.M = 1024; p.N = 512; p.K = 512;
    launchg<32, 64>(p, 2, stream);

    // fused flash attention -> aob
    flash_attn<<<dim3(16, 16), dim3(256), 0, stream>>>(qkb, Vtb, aob);

    // out projection -> t2 fp32
    p = GemmP{}; p.azi = p.bzi = p.czi = 1; p.scale = 1.0f;
    p.A = aob; p.lda = 512; p.B = outwb + (long)l * 262144; p.ldb = 512;
    p.C = t2; p.crs = 512; p.ccs = 1; p.cbf16 = 0;
    p.bias = outb + l * 512;
    p.M = 2048; p.N = 512; p.K = 512;
    launchg<32, 64>(p, 1, stream);

    ln512<<<dim3(512), dim3(256), 0, stream>>>(t2, xin, 1, lng + (l * 3) * 512,
                                               lnbp + (l * 3) * 512, x1, nullptr,
                                               nullptr, nullptr);

    // conv k (memory+pos) and conv v (memory) in ONE batched launch:
    //   z 0,1 -> kT[b];  z 2,3 -> vT[b]
    p = GemmP{}; p.scale = 1.0f;
    p.A = mempb; p.lda = 1024; p.azi = 2; p.aso = 2097152; p.asi = 512;
    p.B = convwb + ((long)l * 3 + 1) * 262144; p.ldb = 512;
    p.bzi = 2; p.bso = 262144; p.bsi = 0;
    p.C = kT; p.crs = 1; p.ccs = 2048;
    p.czi = 2; p.cso = 2097152; p.csi = 1048576; p.cbf16 = 0;
    p.bias = convb + (l * 3 + 1) * 512; p.biasdz = 2; p.biassz = 512;
    p.M = 2048; p.N = 512; p.K = 512;
    launchg<64, 64>(p, 4, stream);

    // custom attention
    xsum1<<<dim3(32), dim3(512), 0, stream>>>(x1, qpos, xpart);
    xsum2<<<dim3(2), dim3(512), 0, stream>>>(xpart, xsumb);
    s1_k<<<dim3(16, 8), dim3(256), 0, stream>>>(xsumb, convw + ((long)l * 3) * 262144,
                                                convb + (l * 3) * 512, kT, s1b);
    pw_k<<<dim3(128), dim3(256), 0, stream>>>(kT, s1b, mlpw + l * 64, pwpart);
    x2_k<<<dim3(16, 4), dim3(256), 0, stream>>>(vT, pwpart, mlpb + l, t2c);

    ln512<<<dim3(512), dim3(256), 0, stream>>>(x1, t2c, 2, lng + (l * 3 + 1) * 512,
                                               lnbp + (l * 3 + 1) * 512, x2n, x2nb,
                                               nullptr, nullptr);

    // FFN
    p = GemmP{}; p.azi = p.bzi = p.czi = 1; p.scale = 1.0f;
    p.A = x2nb; p.lda = 512; p.B = l1wb + (long)l * 1048576; p.ldb = 512;
    p.C = hb; p.crs = 2048; p.ccs = 1; p.cbf16 = 1; p.relu = 1;
    p.bias = l1b + l * 2048;
    p.M = 2048; p.N = 2048; p.K = 512;
    launchg<64, 64>(p, 1, stream);

    p = GemmP{}; p.azi = p.bzi = p.czi = 1; p.scale = 1.0f;
    p.A = hb; p.lda = 2048; p.B = l2wb + (long)l * 1048576; p.ldb = 2048;
    p.C = fbuf; p.crs = 512; p.ccs = 1; p.cbf16 = 0;
    p.bias = l2b + l * 512;
    p.M = 2048; p.N = 512; p.K = 2048;
    launchg<32, 64>(p, 1, stream);

    // LN3 (+ fused bf16 conversions of next layer's x and x+qpos)
    ln512<<<dim3(512), dim3(256), 0, stream>>>(fbuf, x2n, 1, lng + (l * 3 + 2) * 512,
                                               lnbp + (l * 3 + 2) * 512, xbuf, xb,
                                               qpos, xqb);
  }
  ln512<<<dim3(512), dim3(256), 0, stream>>>(xbuf, nullptr, 0, fg, fbv,
                                             (float*)d_out, nullptr, nullptr, nullptr);
}